// Round 1
// baseline (306.493 us; speedup 1.0000x reference)
//
#include <hip/hip_runtime.h>

#define TT 4
#define BB 8
#define CC 256
#define NN 512
#define HEADS 16
#define HD 16

// -----------------------------------------------------------------------------
// Kernel 1: fused 1x1 conv (GEMM over C) + BatchNorm + LIF(v_th=1) over T,
// writing bit-packed spikes: bits[t][b][c][chunk] (chunk = n/64, 8 chunks).
// Grid: (N/64=8, C/64=4, B=8). Block: 256 threads (tx=16 n-groups, ty=16 o-groups).
// -----------------------------------------------------------------------------
__global__ __launch_bounds__(256)
void conv_bn_lif_pack(const float* __restrict__ x,      // [T,B,C,N]
                      const float* __restrict__ w,      // [C,C]
                      const float* __restrict__ gamma,
                      const float* __restrict__ beta,
                      const float* __restrict__ mean,
                      const float* __restrict__ var,
                      unsigned long long* __restrict__ bits) // [T,B,C,8]
{
    __shared__ float Ws[64][68];          // [o][k] (+pad: 68%32=4 -> 2-way max)
    __shared__ float Xs[64][64];          // [k][n]
    __shared__ unsigned short Spk[64][16];// nibble per (o-row, tx)

    const int tid = threadIdx.x;
    const int tx = tid & 15;
    const int ty = tid >> 4;
    const int b  = blockIdx.z;
    const int o0 = blockIdx.y * 64;
    const int n0 = blockIdx.x * 64;

    // Per-channel BN affine, rounded like the reference (mul then sub, no FMA).
    float sc[4], bi[4];
#pragma unroll
    for (int i = 0; i < 4; ++i) {
        int o = o0 + ty * 4 + i;
        float rs = __fdiv_rn(1.0f, __fsqrt_rn(__fadd_rn(var[o], 1e-5f)));
        float s  = __fmul_rn(gamma[o], rs);
        sc[i] = s;
        bi[i] = __fsub_rn(beta[o], __fmul_rn(mean[o], s));
    }

    float vst[4][4];
#pragma unroll
    for (int i = 0; i < 4; ++i)
#pragma unroll
        for (int j = 0; j < 4; ++j) vst[i][j] = 0.0f;

    for (int t = 0; t < TT; ++t) {
        float acc[4][4];
#pragma unroll
        for (int i = 0; i < 4; ++i)
#pragma unroll
            for (int j = 0; j < 4; ++j) acc[i][j] = 0.0f;

        const float* xb = x + (size_t)(t * BB + b) * CC * NN;

        for (int k0 = 0; k0 < CC; k0 += 64) {
            __syncthreads();
#pragma unroll
            for (int i = 0; i < 4; ++i) {
                int idx = tid + 256 * i;      // 0..1023
                int row = idx >> 4;           // 0..63
                int cg  = idx & 15;           // float4 group
                float4 wv = *reinterpret_cast<const float4*>(
                    &w[(size_t)(o0 + row) * CC + k0 + cg * 4]);
                *reinterpret_cast<float4*>(&Ws[row][cg * 4]) = wv;
                float4 xv = *reinterpret_cast<const float4*>(
                    &xb[(size_t)(k0 + row) * NN + n0 + cg * 4]);
                *reinterpret_cast<float4*>(&Xs[row][cg * 4]) = xv;
            }
            __syncthreads();
#pragma unroll 4
            for (int kk = 0; kk < 64; ++kk) {
                float4 xv = *reinterpret_cast<const float4*>(&Xs[kk][tx * 4]);
#pragma unroll
                for (int i = 0; i < 4; ++i) {
                    float wv = Ws[ty * 4 + i][kk];
                    acc[i][0] = __fmaf_rn(wv, xv.x, acc[i][0]);
                    acc[i][1] = __fmaf_rn(wv, xv.y, acc[i][1]);
                    acc[i][2] = __fmaf_rn(wv, xv.z, acc[i][2]);
                    acc[i][3] = __fmaf_rn(wv, xv.w, acc[i][3]);
                }
            }
        }

        // BN + LIF (h = v + (x-v)*0.5 ; spike = h>=1 ; v = spike?0:h)
        unsigned int nib[4] = {0u, 0u, 0u, 0u};
#pragma unroll
        for (int i = 0; i < 4; ++i) {
#pragma unroll
            for (int j = 0; j < 4; ++j) {
                float ybn = __fadd_rn(__fmul_rn(acc[i][j], sc[i]), bi[i]);
                float h   = __fadd_rn(vst[i][j],
                                      __fmul_rn(__fsub_rn(ybn, vst[i][j]), 0.5f));
                bool sp = (h >= 1.0f);
                vst[i][j] = sp ? 0.0f : h;
                nib[i] |= (sp ? 1u : 0u) << j;
            }
        }
        __syncthreads();
#pragma unroll
        for (int i = 0; i < 4; ++i) Spk[ty * 4 + i][tx] = (unsigned short)nib[i];
        __syncthreads();
        if (tid < 64) {
            unsigned long long m = 0ULL;
#pragma unroll
            for (int g = 0; g < 16; ++g)
                m |= (unsigned long long)(Spk[tid][g] & 0xF) << (4 * g);
            bits[((size_t)(t * BB + b) * CC + o0 + tid) * 8 + blockIdx.x] = m;
        }
    }
}

// -----------------------------------------------------------------------------
// Kernel 2: attention via M = K^T V (16x16 integer popcounts), Y = 0.25 * Q M.
// Exact integer arithmetic -> bit-identical to reference attention.
// Grid: 512 blocks (tb*16 + h). Block: 256 threads.
// -----------------------------------------------------------------------------
__global__ __launch_bounds__(256)
void attn_kernel(const unsigned long long* __restrict__ bq,
                 const unsigned long long* __restrict__ bk,
                 const unsigned long long* __restrict__ bv,
                 float* __restrict__ y) // [32,C,N]
{
    const int blk = blockIdx.x;
    const int h  = blk & 15;
    const int tb = blk >> 4;
    const int tid = threadIdx.x;

    __shared__ unsigned long long kb[16][8], vb[16][8], qb[16][8];
    __shared__ float M[16][16];
    __shared__ float yt[16][512]; // 32 KB

    size_t base = ((size_t)tb * CC + h * HD) * 8;
    if (tid < 128) {
        int j = tid >> 3, ch = tid & 7;
        kb[j][ch] = bk[base + j * 8 + ch];
        vb[j][ch] = bv[base + j * 8 + ch];
        qb[j][ch] = bq[base + j * 8 + ch];
    }
    __syncthreads();

    {
        int j = tid >> 4, d = tid & 15;
        int cnt = 0;
#pragma unroll
        for (int ch = 0; ch < 8; ++ch)
            cnt += __popcll(kb[j][ch] & vb[d][ch]);
        M[j][d] = (float)cnt;
    }
    __syncthreads();

#pragma unroll
    for (int r = 0; r < 2; ++r) {
        int n = tid + 256 * r;
        int ch = n >> 6, sh = n & 63;
        float acc[16];
#pragma unroll
        for (int d = 0; d < 16; ++d) acc[d] = 0.0f;
#pragma unroll
        for (int j = 0; j < 16; ++j) {
            float bit = (float)((qb[j][ch] >> sh) & 1ULL);
#pragma unroll
            for (int d = 0; d < 16; ++d)
                acc[d] = __fmaf_rn(bit, M[j][d], acc[d]);
        }
#pragma unroll
        for (int d = 0; d < 16; ++d) yt[d][n] = __fmul_rn(acc[d], 0.25f);
    }
    __syncthreads();

    size_t ybase = ((size_t)tb * CC + h * HD) * (size_t)NN;
    for (int i = 0; i < 32; ++i) {
        int f = tid + 256 * i;     // 0..8191
        int d = f >> 9, n = f & 511;
        y[ybase + (size_t)d * NN + n] = yt[d][n];
    }
}

// -----------------------------------------------------------------------------
// Kernel 3: attn LIF over T*B=32 sequential steps, v_th=0.5, spikes -> u8.
// Grid: 512 blocks x 256 threads = 131072 threads, one per (c,n).
// -----------------------------------------------------------------------------
__global__ __launch_bounds__(256)
void attn_lif(const float* __restrict__ y, unsigned char* __restrict__ s)
{
    const int e = blockIdx.x * 256 + threadIdx.x; // < 131072
    float v = 0.0f;
    for (int tb = 0; tb < 32; ++tb) {
        float xv = y[(size_t)tb * (CC * NN) + e];
        float h  = __fadd_rn(v, __fmul_rn(__fsub_rn(xv, v), 0.5f));
        bool sp = (h >= 0.5f);
        s[(size_t)tb * (CC * NN) + e] = sp ? 1 : 0;
        v = sp ? 0.0f : h;
    }
}

// -----------------------------------------------------------------------------
// Kernel 4: proj 1x1 conv on binary spikes + BN + final LIF(v_th=1) over T,
// writes f32 spikes to d_out (layout [T,B,C,N] == [T,B,C,W,H] flat).
// Grid: (8,4,8). Block 256.
// -----------------------------------------------------------------------------
__global__ __launch_bounds__(256)
void proj_bn_lif(const unsigned char* __restrict__ s, // [32,C,N]
                 const float* __restrict__ w,
                 const float* __restrict__ gamma,
                 const float* __restrict__ beta,
                 const float* __restrict__ mean,
                 const float* __restrict__ var,
                 float* __restrict__ out)
{
    __shared__ float Ws[64][68];
    __shared__ float Xs[64][64];

    const int tid = threadIdx.x;
    const int tx = tid & 15;
    const int ty = tid >> 4;
    const int b  = blockIdx.z;
    const int o0 = blockIdx.y * 64;
    const int n0 = blockIdx.x * 64;

    float sc[4], bi[4];
#pragma unroll
    for (int i = 0; i < 4; ++i) {
        int o = o0 + ty * 4 + i;
        float rs = __fdiv_rn(1.0f, __fsqrt_rn(__fadd_rn(var[o], 1e-5f)));
        float sv = __fmul_rn(gamma[o], rs);
        sc[i] = sv;
        bi[i] = __fsub_rn(beta[o], __fmul_rn(mean[o], sv));
    }

    float vst[4][4];
#pragma unroll
    for (int i = 0; i < 4; ++i)
#pragma unroll
        for (int j = 0; j < 4; ++j) vst[i][j] = 0.0f;

    for (int t = 0; t < TT; ++t) {
        float acc[4][4];
#pragma unroll
        for (int i = 0; i < 4; ++i)
#pragma unroll
            for (int j = 0; j < 4; ++j) acc[i][j] = 0.0f;

        const unsigned char* sb = s + (size_t)(t * BB + b) * CC * NN;

        for (int k0 = 0; k0 < CC; k0 += 64) {
            __syncthreads();
#pragma unroll
            for (int i = 0; i < 4; ++i) {
                int idx = tid + 256 * i;
                int row = idx >> 4;
                int cg  = idx & 15;
                float4 wv = *reinterpret_cast<const float4*>(
                    &w[(size_t)(o0 + row) * CC + k0 + cg * 4]);
                *reinterpret_cast<float4*>(&Ws[row][cg * 4]) = wv;
                uchar4 uv = *reinterpret_cast<const uchar4*>(
                    &sb[(size_t)(k0 + row) * NN + n0 + cg * 4]);
                Xs[row][cg * 4 + 0] = (float)uv.x;
                Xs[row][cg * 4 + 1] = (float)uv.y;
                Xs[row][cg * 4 + 2] = (float)uv.z;
                Xs[row][cg * 4 + 3] = (float)uv.w;
            }
            __syncthreads();
#pragma unroll 4
            for (int kk = 0; kk < 64; ++kk) {
                float4 xv = *reinterpret_cast<const float4*>(&Xs[kk][tx * 4]);
#pragma unroll
                for (int i = 0; i < 4; ++i) {
                    float wv = Ws[ty * 4 + i][kk];
                    acc[i][0] = __fmaf_rn(wv, xv.x, acc[i][0]);
                    acc[i][1] = __fmaf_rn(wv, xv.y, acc[i][1]);
                    acc[i][2] = __fmaf_rn(wv, xv.z, acc[i][2]);
                    acc[i][3] = __fmaf_rn(wv, xv.w, acc[i][3]);
                }
            }
        }

#pragma unroll
        for (int i = 0; i < 4; ++i) {
            float4 o4;
            float r[4];
#pragma unroll
            for (int j = 0; j < 4; ++j) {
                float ybn = __fadd_rn(__fmul_rn(acc[i][j], sc[i]), bi[i]);
                float h   = __fadd_rn(vst[i][j],
                                      __fmul_rn(__fsub_rn(ybn, vst[i][j]), 0.5f));
                bool sp = (h >= 1.0f);
                vst[i][j] = sp ? 0.0f : h;
                r[j] = sp ? 1.0f : 0.0f;
            }
            o4.x = r[0]; o4.y = r[1]; o4.z = r[2]; o4.w = r[3];
            *reinterpret_cast<float4*>(
                &out[((size_t)(t * BB + b) * CC + o0 + ty * 4 + i) * NN + n0 + tx * 4]) = o4;
        }
    }
}

// -----------------------------------------------------------------------------
extern "C" void kernel_launch(void* const* d_in, const int* in_sizes, int n_in,
                              void* d_out, int out_size, void* d_ws, size_t ws_size,
                              hipStream_t stream) {
    const float* x  = (const float*)d_in[0];
    const float* qw = (const float*)d_in[1];
    const float* qg = (const float*)d_in[2];
    const float* qb = (const float*)d_in[3];
    const float* qm = (const float*)d_in[4];
    const float* qv = (const float*)d_in[5];
    const float* kw = (const float*)d_in[6];
    const float* kg = (const float*)d_in[7];
    const float* kb = (const float*)d_in[8];
    const float* km = (const float*)d_in[9];
    const float* kv = (const float*)d_in[10];
    const float* vw = (const float*)d_in[11];
    const float* vg = (const float*)d_in[12];
    const float* vb = (const float*)d_in[13];
    const float* vm = (const float*)d_in[14];
    const float* vv = (const float*)d_in[15];
    const float* pw = (const float*)d_in[16];
    const float* pg = (const float*)d_in[17];
    const float* pb = (const float*)d_in[18];
    const float* pm = (const float*)d_in[19];
    const float* pv = (const float*)d_in[20];

    char* ws = (char*)d_ws;
    unsigned long long* bitsq = (unsigned long long*)(ws);                       // 512 KB
    unsigned long long* bitsk = (unsigned long long*)(ws + (512u << 10));        // 512 KB
    unsigned long long* bitsv = (unsigned long long*)(ws + (1024u << 10));       // 512 KB
    float*              ybuf  = (float*)(ws + (1536u << 10));                    // 16 MB
    unsigned char*      sbuf  = (unsigned char*)(ws + (1536u << 10) + (16u << 20)); // 4 MB

    dim3 g1(8, 4, 8), blk(256);
    conv_bn_lif_pack<<<g1, blk, 0, stream>>>(x, qw, qg, qb, qm, qv, bitsq);
    conv_bn_lif_pack<<<g1, blk, 0, stream>>>(x, kw, kg, kb, km, kv, bitsk);
    conv_bn_lif_pack<<<g1, blk, 0, stream>>>(x, vw, vg, vb, vm, vv, bitsv);
    attn_kernel<<<512, blk, 0, stream>>>(bitsq, bitsk, bitsv, ybuf);
    attn_lif<<<512, blk, 0, stream>>>(ybuf, sbuf);
    proj_bn_lif<<<g1, blk, 0, stream>>>(sbuf, pw, pg, pb, pm, pv, (float*)d_out);
}

// Round 2
// 263.880 us; speedup vs baseline: 1.1615x; 1.1615x over previous
//
#include <hip/hip_runtime.h>

#define TT 4
#define BB 8
#define CC 256
#define NN 512
#define HEADS 16
#define HD 16

#define GLL16(gp, lp) \
    __builtin_amdgcn_global_load_lds( \
        (const __attribute__((address_space(1))) void*)(gp), \
        (__attribute__((address_space(3))) void*)(lp), 16, 0, 0)

struct WPtrs  { const float* w[4]; };
struct BnPtrs { const float* g[4]; const float* b[4]; const float* m[4]; const float* v[4]; };

// -----------------------------------------------------------------------------
// Prep 1: BN affine (sc, bi) per channel, exact same fp32 ops as before.
// grid(4), block(256): m = blockIdx.x, c = threadIdx.x.
// -----------------------------------------------------------------------------
__global__ __launch_bounds__(256)
void prep_bn(BnPtrs p, float* __restrict__ sc, float* __restrict__ bi)
{
    int m = blockIdx.x, c = threadIdx.x;
    float rs = __fdiv_rn(1.0f, __fsqrt_rn(__fadd_rn(p.v[m][c], 1e-5f)));
    float s  = __fmul_rn(p.g[m][c], rs);
    sc[m * CC + c] = s;
    bi[m * CC + c] = __fsub_rn(p.b[m][c], __fmul_rn(p.m[m][c], s));
}

// -----------------------------------------------------------------------------
// Prep 2: transpose 4 weight matrices: wt[m][k][o] = w_m[o][k].
// grid(16,16,4), block(16,16).
// -----------------------------------------------------------------------------
__global__ __launch_bounds__(256)
void transpose_w(WPtrs p, float* __restrict__ wt)
{
    __shared__ float t[16][17];
    const int m  = blockIdx.z;
    const float* w = p.w[m];
    const int o0 = blockIdx.y * 16, k0 = blockIdx.x * 16;
    const int tx = threadIdx.x, ty = threadIdx.y;
    t[ty][tx] = w[(size_t)(o0 + ty) * CC + k0 + tx];
    __syncthreads();
    wt[(size_t)m * CC * CC + (size_t)(k0 + ty) * CC + o0 + tx] = t[tx][ty];
}

// -----------------------------------------------------------------------------
// Kernel 1: fused q/k/v 1x1 conv + BN + LIF(v_th=1) over T, bit-packed spikes.
// grid (8, 4, 24): z = branch*8 + b. block 256 (tx 16 n-quads, ty 16 o-quads).
// Both operands staged with global_load_lds (linear layouts); b128 LDS reads.
// -----------------------------------------------------------------------------
__global__ __launch_bounds__(256)
void qkv_conv_bn_lif_pack(const float* __restrict__ x,     // [T,B,C,N]
                          const float* __restrict__ wt,    // [3][C][C] (k-major)
                          const float* __restrict__ scA,   // [4][C]
                          const float* __restrict__ biA,
                          unsigned long long* __restrict__ bits) // [3][T*B*C*8]
{
    __shared__ float WtS[64][64];          // [k][o]
    __shared__ float Xs[64][64];           // [k][n]
    __shared__ unsigned short Spk[64][16];

    const int tid = threadIdx.x;
    const int tx = tid & 15;
    const int ty = tid >> 4;
    const int br = blockIdx.z >> 3;
    const int b  = blockIdx.z & 7;
    const int o0 = blockIdx.y * 64;
    const int n0 = blockIdx.x * 64;

    const float* wtb = wt + (size_t)br * CC * CC;
    unsigned long long* bout = bits + (size_t)br * (TT * BB * CC * 8);

    float sc[4], bi[4];
#pragma unroll
    for (int i = 0; i < 4; ++i) {
        sc[i] = scA[br * CC + o0 + ty * 4 + i];
        bi[i] = biA[br * CC + o0 + ty * 4 + i];
    }

    float vst[4][4];
#pragma unroll
    for (int i = 0; i < 4; ++i)
#pragma unroll
        for (int j = 0; j < 4; ++j) vst[i][j] = 0.0f;

    for (int t = 0; t < TT; ++t) {
        float acc[4][4];
#pragma unroll
        for (int i = 0; i < 4; ++i)
#pragma unroll
            for (int j = 0; j < 4; ++j) acc[i][j] = 0.0f;

        const float* xb = x + (size_t)(t * BB + b) * CC * NN;

        for (int k0 = 0; k0 < CC; k0 += 64) {
            __syncthreads();
#pragma unroll
            for (int i = 0; i < 4; ++i) {
                int idx = tid + 256 * i;      // 0..1023
                int row = idx >> 4;           // k row 0..63
                int cg  = idx & 15;           // float4 col group
                GLL16(&wtb[(size_t)(k0 + row) * CC + o0 + cg * 4], &WtS[row][cg * 4]);
                GLL16(&xb [(size_t)(k0 + row) * NN + n0 + cg * 4], &Xs [row][cg * 4]);
            }
            __syncthreads();
#pragma unroll 8
            for (int kk = 0; kk < 64; ++kk) {
                float4 wv = *reinterpret_cast<const float4*>(&WtS[kk][ty * 4]);
                float4 xv = *reinterpret_cast<const float4*>(&Xs[kk][tx * 4]);
#pragma unroll
                for (int i = 0; i < 4; ++i) {
                    float wvi = (i == 0) ? wv.x : (i == 1) ? wv.y : (i == 2) ? wv.z : wv.w;
                    acc[i][0] = __fmaf_rn(wvi, xv.x, acc[i][0]);
                    acc[i][1] = __fmaf_rn(wvi, xv.y, acc[i][1]);
                    acc[i][2] = __fmaf_rn(wvi, xv.z, acc[i][2]);
                    acc[i][3] = __fmaf_rn(wvi, xv.w, acc[i][3]);
                }
            }
        }

        // BN + LIF: h = v + (ybn - v)*0.5; spike = h>=1; v = spike?0:h
        unsigned int nib[4] = {0u, 0u, 0u, 0u};
#pragma unroll
        for (int i = 0; i < 4; ++i) {
#pragma unroll
            for (int j = 0; j < 4; ++j) {
                float ybn = __fadd_rn(__fmul_rn(acc[i][j], sc[i]), bi[i]);
                float h   = __fadd_rn(vst[i][j],
                                      __fmul_rn(__fsub_rn(ybn, vst[i][j]), 0.5f));
                bool sp = (h >= 1.0f);
                vst[i][j] = sp ? 0.0f : h;
                nib[i] |= (sp ? 1u : 0u) << j;
            }
        }
        __syncthreads();
#pragma unroll
        for (int i = 0; i < 4; ++i) Spk[ty * 4 + i][tx] = (unsigned short)nib[i];
        __syncthreads();
        if (tid < 64) {
            unsigned long long m = 0ULL;
#pragma unroll
            for (int g = 0; g < 16; ++g)
                m |= (unsigned long long)(Spk[tid][g] & 0xF) << (4 * g);
            bout[((size_t)(t * BB + b) * CC + o0 + tid) * 8 + blockIdx.x] = m;
        }
    }
}

// -----------------------------------------------------------------------------
// Kernel 2: attention via M = K^T V (16x16 integer popcounts), Y = 0.25 * Q M.
// Exact integer arithmetic. Direct coalesced stores (no LDS bounce).
// grid 512 (tb*16+h), block 256.
// -----------------------------------------------------------------------------
__global__ __launch_bounds__(256)
void attn_kernel(const unsigned long long* __restrict__ bq,
                 const unsigned long long* __restrict__ bk,
                 const unsigned long long* __restrict__ bv,
                 float* __restrict__ y) // [32,C,N]
{
    const int blk = blockIdx.x;
    const int h  = blk & 15;
    const int tb = blk >> 4;
    const int tid = threadIdx.x;

    __shared__ unsigned long long kb[16][8], vb[16][8], qb[16][8];
    __shared__ float M[16][16];

    size_t base = ((size_t)tb * CC + h * HD) * 8;
    if (tid < 128) {
        int j = tid >> 3, ch = tid & 7;
        kb[j][ch] = bk[base + j * 8 + ch];
        vb[j][ch] = bv[base + j * 8 + ch];
        qb[j][ch] = bq[base + j * 8 + ch];
    }
    __syncthreads();

    {
        int j = tid >> 4, d = tid & 15;
        int cnt = 0;
#pragma unroll
        for (int ch = 0; ch < 8; ++ch)
            cnt += __popcll(kb[j][ch] & vb[d][ch]);
        M[j][d] = (float)cnt;
    }
    __syncthreads();

    size_t ybase = ((size_t)tb * CC + h * HD) * (size_t)NN;
#pragma unroll
    for (int r = 0; r < 2; ++r) {
        int n = tid + 256 * r;
        int ch = n >> 6, sh = n & 63;
        float acc[16];
#pragma unroll
        for (int d = 0; d < 16; ++d) acc[d] = 0.0f;
#pragma unroll
        for (int j = 0; j < 16; ++j) {
            float bit = (float)((qb[j][ch] >> sh) & 1ULL);
#pragma unroll
            for (int d = 0; d < 16; ++d)
                acc[d] = __fmaf_rn(bit, M[j][d], acc[d]);
        }
#pragma unroll
        for (int d = 0; d < 16; ++d)
            y[ybase + (size_t)d * NN + n] = __fmul_rn(acc[d], 0.25f);
    }
}

// -----------------------------------------------------------------------------
// Kernel 3: attn LIF over 32 sequential steps, v_th=0.5, float4-vectorized.
// grid 128, block 256: each thread owns 4 consecutive (c,n) elements.
// -----------------------------------------------------------------------------
__global__ __launch_bounds__(256)
void attn_lif(const float* __restrict__ y, unsigned char* __restrict__ s)
{
    const int e4 = blockIdx.x * 256 + threadIdx.x; // < 32768
    float4 v = make_float4(0.f, 0.f, 0.f, 0.f);
    for (int tb = 0; tb < 32; ++tb) {
        float4 xv = *reinterpret_cast<const float4*>(&y[(size_t)tb * (CC * NN) + e4 * 4]);
        uchar4 o;
        float h;
        h = __fadd_rn(v.x, __fmul_rn(__fsub_rn(xv.x, v.x), 0.5f));
        o.x = (h >= 0.5f) ? 1 : 0; v.x = (h >= 0.5f) ? 0.0f : h;
        h = __fadd_rn(v.y, __fmul_rn(__fsub_rn(xv.y, v.y), 0.5f));
        o.y = (h >= 0.5f) ? 1 : 0; v.y = (h >= 0.5f) ? 0.0f : h;
        h = __fadd_rn(v.z, __fmul_rn(__fsub_rn(xv.z, v.z), 0.5f));
        o.z = (h >= 0.5f) ? 1 : 0; v.z = (h >= 0.5f) ? 0.0f : h;
        h = __fadd_rn(v.w, __fmul_rn(__fsub_rn(xv.w, v.w), 0.5f));
        o.w = (h >= 0.5f) ? 1 : 0; v.w = (h >= 0.5f) ? 0.0f : h;
        *reinterpret_cast<uchar4*>(&s[(size_t)tb * (CC * NN) + e4 * 4]) = o;
    }
}

// -----------------------------------------------------------------------------
// Kernel 4: proj conv on binary spikes + BN + final LIF(v_th=1), f32 out.
// grid (16,4,8): 64x32 (o x n) tiles -> 512 blocks (2/CU). block 256:
// tx 16 n-pairs, ty 16 o-quads. W via global_load_lds; X u8->f32 via VGPR.
// -----------------------------------------------------------------------------
__global__ __launch_bounds__(256)
void proj_bn_lif(const unsigned char* __restrict__ s, // [32,C,N]
                 const float* __restrict__ wt,        // [C][C] k-major (m=3)
                 const float* __restrict__ scA,       // [4][C]
                 const float* __restrict__ biA,
                 float* __restrict__ out)
{
    __shared__ float WtS[64][64];  // [k][o]
    __shared__ float Xs[64][36];   // [k][n] (+4 pad, keeps 16B align)

    const int tid = threadIdx.x;
    const int tx = tid & 15;
    const int ty = tid >> 4;
    const int b  = blockIdx.z;
    const int o0 = blockIdx.y * 64;
    const int n0 = blockIdx.x * 32;

    float sc[4], bi[4];
#pragma unroll
    for (int i = 0; i < 4; ++i) {
        sc[i] = scA[3 * CC + o0 + ty * 4 + i];
        bi[i] = biA[3 * CC + o0 + ty * 4 + i];
    }

    float vst[4][2];
#pragma unroll
    for (int i = 0; i < 4; ++i) { vst[i][0] = 0.0f; vst[i][1] = 0.0f; }

    for (int t = 0; t < TT; ++t) {
        float acc[4][2];
#pragma unroll
        for (int i = 0; i < 4; ++i) { acc[i][0] = 0.0f; acc[i][1] = 0.0f; }

        const unsigned char* sb = s + (size_t)(t * BB + b) * CC * NN;

        for (int k0 = 0; k0 < CC; k0 += 64) {
            __syncthreads();
#pragma unroll
            for (int i = 0; i < 4; ++i) {
                int idx = tid + 256 * i;
                int row = idx >> 4, cg = idx & 15;
                GLL16(&wt[(size_t)(k0 + row) * CC + o0 + cg * 4], &WtS[row][cg * 4]);
            }
#pragma unroll
            for (int i = 0; i < 2; ++i) {
                int idx = tid + 256 * i;      // 0..511
                int row = idx >> 3, seg = idx & 7;
                uchar4 u = *reinterpret_cast<const uchar4*>(
                    &sb[(size_t)(k0 + row) * NN + n0 + seg * 4]);
                float4 f = make_float4((float)u.x, (float)u.y, (float)u.z, (float)u.w);
                *reinterpret_cast<float4*>(&Xs[row][seg * 4]) = f;
            }
            __syncthreads();
#pragma unroll 8
            for (int kk = 0; kk < 64; ++kk) {
                float4 wv = *reinterpret_cast<const float4*>(&WtS[kk][ty * 4]);
                float2 xv = *reinterpret_cast<const float2*>(&Xs[kk][tx * 2]);
#pragma unroll
                for (int i = 0; i < 4; ++i) {
                    float wvi = (i == 0) ? wv.x : (i == 1) ? wv.y : (i == 2) ? wv.z : wv.w;
                    acc[i][0] = __fmaf_rn(wvi, xv.x, acc[i][0]);
                    acc[i][1] = __fmaf_rn(wvi, xv.y, acc[i][1]);
                }
            }
        }

#pragma unroll
        for (int i = 0; i < 4; ++i) {
            float2 o2;
            float r[2];
#pragma unroll
            for (int j = 0; j < 2; ++j) {
                float ybn = __fadd_rn(__fmul_rn(acc[i][j], sc[i]), bi[i]);
                float h   = __fadd_rn(vst[i][j],
                                      __fmul_rn(__fsub_rn(ybn, vst[i][j]), 0.5f));
                bool sp = (h >= 1.0f);
                vst[i][j] = sp ? 0.0f : h;
                r[j] = sp ? 1.0f : 0.0f;
            }
            o2.x = r[0]; o2.y = r[1];
            *reinterpret_cast<float2*>(
                &out[((size_t)(t * BB + b) * CC + o0 + ty * 4 + i) * NN + n0 + tx * 2]) = o2;
        }
    }
}

// -----------------------------------------------------------------------------
extern "C" void kernel_launch(void* const* d_in, const int* in_sizes, int n_in,
                              void* d_out, int out_size, void* d_ws, size_t ws_size,
                              hipStream_t stream) {
    const float* x = (const float*)d_in[0];

    WPtrs wp;
    BnPtrs bp;
    // order: q(1..5), k(6..10), v(11..15), proj(16..20); each: w,g,b,m,v
    for (int m = 0; m < 4; ++m) {
        wp.w[m] = (const float*)d_in[1 + m * 5 + 0];
        bp.g[m] = (const float*)d_in[1 + m * 5 + 1];
        bp.b[m] = (const float*)d_in[1 + m * 5 + 2];
        bp.m[m] = (const float*)d_in[1 + m * 5 + 3];
        bp.v[m] = (const float*)d_in[1 + m * 5 + 4];
    }

    char* ws = (char*)d_ws;
    float* wt   = (float*)ws;                                   // 4*256*256*4 = 1 MB
    float* scA  = (float*)(ws + (1u << 20));                    // 4 KB
    float* biA  = (float*)(ws + (1u << 20) + 4096);             // 4 KB
    unsigned long long* bits = (unsigned long long*)(ws + (1u << 20) + 8192); // 1.5 MB
    float* ybuf = (float*)(ws + (1u << 20) + 8192 + (1536u << 10));           // 16 MB
    unsigned char* sbuf = (unsigned char*)(ws + (1u << 20) + 8192 + (1536u << 10) + (16u << 20)); // 4 MB

    prep_bn<<<4, 256, 0, stream>>>(bp, scA, biA);
    transpose_w<<<dim3(16, 16, 4), dim3(16, 16), 0, stream>>>(wp, wt);

    qkv_conv_bn_lif_pack<<<dim3(8, 4, 24), 256, 0, stream>>>(x, wt, scA, biA, bits);

    const unsigned long long* bq = bits;
    const unsigned long long* bk = bits + 65536;
    const unsigned long long* bv = bits + 131072;
    attn_kernel<<<512, 256, 0, stream>>>(bq, bk, bv, ybuf);
    attn_lif<<<128, 256, 0, stream>>>(ybuf, sbuf);
    proj_bn_lif<<<dim3(16, 4, 8), 256, 0, stream>>>(sbuf, wt + 3 * CC * CC, scA, biA, (float*)d_out);
}